// Round 8
// baseline (296.316 us; speedup 1.0000x reference)
//
#include <hip/hip_runtime.h>

typedef unsigned long long u64;
typedef unsigned int u32;
typedef unsigned short u16;
typedef float f2 __attribute__((ext_vector_type(2)));
typedef float f4 __attribute__((ext_vector_type(4)));

// Problem constants (match reference setup_inputs)
#define NSETS 8
#define NPTS  4096
#define DF    16
#define KNN   16
#define QPB   64                  // queries per block (one per lane)
#define NCH   8                   // waves per block
#define BLK   (QPB * NCH)         // 512 threads
#define TILE  512                 // candidates staged into LDS per tile
#define NTILE (NPTS / TILE)       // 8
#define SLICE (TILE / NCH)        // 64 candidates per wave per tile
#define PAIRS_W (SLICE / 2)       // 32 pairs per wave per tile
#define NEDGE (NSETS * NPTS * KNN)

// Round-15: the VGPR hypothesis is confirmed (r11/60+r14/56 -> 36-37% occ;
// r12/76+r13/80 -> 21% at the SAME LDS). The pk-FMA pair scan does ~26%
// less VALU work (r12: 93us-equiv vs r11's 126, occupancy-independent) but
// twice died to VGPR>64. r15 defuses it: __launch_bounds__(512,8) caps the
// allocator at 512/8 = 64 VGPR (coldest state = Lk, drain-only, is the
// natural spill victim if any). Also reverts r13's branchless every-
// candidate stores (3.99M bank conflicts) to GATED inserts (r14: 232k).
// Everything else = r13 verbatim (passed, bit-identical output): pair-
// interleaved pf planes, prt split norms (exact Phase-A tree), u16 idx
// plane, RES12/FLUSH9 drain with sort8+keep+merge16 and rare sort4 round,
// tau2 global fold, MPAD merge.
#define RES      12               // append-list slots/lane
#define FLUSH_AT 9                // drain when any lane cnt >= this (post-group)
#define GRPP     2                // PAIRS between drain checks (=4 candidates)

#define PF_B     (TILE * DF * 4)            // 32768 B: pf[8][256] f4 pair-planes
#define PRT_OFF  PF_B                       // 4096 B: prt[2][256] f2 half-norms
#define RESV_OFF (PF_B + 4096)              // 36864: dist plane (f32)
#define RESI_OFF (RESV_OFF + RES * BLK * 4) // 61440: idx plane (u16)
#define SMEM_B   (RESI_OFF + RES * BLK * 2) // 73728 B (+2304 tau -> 2 blocks/CU)
#define MPAD     17                         // merge-overlay stride (17 coprime 32)

// positive/negative-safe orderable-uint mapping for f32 (handles the ~±0
// diagonal self-distance)
__device__ __forceinline__ unsigned flip_f(float d) {
    unsigned b = __float_as_uint(d);
    return (b & 0x80000000u) ? ~b : (b | 0x80000000u);
}
__device__ __forceinline__ float unflip_f(unsigned u) {
    unsigned b = (u & 0x80000000u) ? (u ^ 0x80000000u) : ~u;
    return __uint_as_float(b);
}

__device__ __forceinline__ f2 sp2(float v) { f2 r = {v, v}; return r; }

__device__ __forceinline__ f2 fma2(f2 a, f2 b, f2 c) {
#if __has_builtin(__builtin_elementwise_fma)
    return __builtin_elementwise_fma(a, b, c);
#else
    f2 r; r.x = fmaf(a.x, b.x, c.x); r.y = fmaf(a.y, b.y, c.y); return r;
#endif
}

// compare-exchange: ascending (min at i), u64 key carries (dist, idx)
#define CEB(i, j) { u64 _a = B[i], _b = B[j]; bool _c = _b < _a; \
                    B[i] = _c ? _b : _a; B[j] = _c ? _a : _b; }
#define CEC(i, j) { u64 _a = C[i], _b = C[j]; bool _c = _b < _a; \
                    C[i] = _c ? _b : _a; C[j] = _c ? _a : _b; }
#define CEL(i, j) { u64 _a = Lk[i], _b = Lk[j]; bool _c = _b < _a; \
                    Lk[i] = _c ? _b : _a; Lk[j] = _c ? _a : _b; }
// bitonic merge 16 -> ascending (Lk[0..7] asc, tail from min-pair => bitonic)
#define MERGE16() \
    CEL(0,8)  CEL(1,9)  CEL(2,10) CEL(3,11)  \
    CEL(4,12) CEL(5,13) CEL(6,14) CEL(7,15)  \
    CEL(0,4)  CEL(1,5)  CEL(2,6)  CEL(3,7)   \
    CEL(8,12) CEL(9,13) CEL(10,14) CEL(11,15) \
    CEL(0,2)  CEL(1,3)  CEL(4,6)  CEL(5,7)   \
    CEL(8,10) CEL(9,11) CEL(12,14) CEL(13,15) \
    CEL(0,1)  CEL(2,3)  CEL(4,5)  CEL(6,7)   \
    CEL(8,9)  CEL(10,11) CEL(12,13) CEL(14,15)

__global__ __launch_bounds__(BLK, 8) void knn_kernel(const float* __restrict__ x,
                                                     float* __restrict__ out) {
    __shared__ float tau_sh[QPB];                 // shared per-query tau (min fold)
    __shared__ float tau2_sh[NCH * QPB];          // per-wave 2nd-smallest per query
    __shared__ __align__(16) char smem[SMEM_B];
    f4*    pf   = (f4*)smem;                      // pf[j*256 + p], j=0..7 dim-pairs
    f2*    prt  = (f2*)(smem + PRT_OFF);          // prt[hf*256 + p] half-norm pairs
    float* resd = (float*)(smem + RESV_OFF);      // reservoir dist plane (f32)
    u16*   resi = (u16*)(smem + RESI_OFF);        // reservoir idx plane (u16)
    float*          lds_d = (float*)smem;                     // overlay (post-scan)
    unsigned short* lds_i = (unsigned short*)(smem + BLK * MPAD * 4);

    const int t    = threadIdx.x;
    const int lane = t & 63;
    const int wv   = t >> 6;                    // slice index 0..7
    const int set  = blockIdx.x >> 6;           // 64 blocks per set
    const int q0   = (blockIdx.x & 63) * QPB;
    const int q    = q0 + lane;                 // this lane's query point

    const float* xs = x + (size_t)set * NPTS * DF;

    if (t < QPB) tau_sh[t] = 3.0e38f;
    tau2_sh[t] = 3.0e38f;                       // BLK == NCH*QPB, full coverage

    // Query features; q2 via the SAME pairwise tree as candidate norms (bit-
    // identical to prior rounds). qn = -2*q: exact pow2 scaling commutes with
    // fma rounding -> dist bit-identical to r11.
    float qn[DF];
    float q2;
    {
        const float4* qp = (const float4*)(xs + (size_t)q * DF);
        float4 a = qp[0], b = qp[1], g = qp[2], d = qp[3];
        float r0 = __fadd_rn(__fmul_rn(a.x, a.x), __fmul_rn(g.x, g.x));
        float r1 = __fadd_rn(__fmul_rn(a.y, a.y), __fmul_rn(g.y, g.y));
        float r2 = __fadd_rn(__fmul_rn(a.z, a.z), __fmul_rn(g.z, g.z));
        float r3 = __fadd_rn(__fmul_rn(a.w, a.w), __fmul_rn(g.w, g.w));
        float r4 = __fadd_rn(__fmul_rn(b.x, b.x), __fmul_rn(d.x, d.x));
        float r5 = __fadd_rn(__fmul_rn(b.y, b.y), __fmul_rn(d.y, d.y));
        float r6 = __fadd_rn(__fmul_rn(b.z, b.z), __fmul_rn(d.z, d.z));
        float r7 = __fadd_rn(__fmul_rn(b.w, b.w), __fmul_rn(d.w, d.w));
        q2 = __fadd_rn(__fadd_rn(__fadd_rn(r0, r1), __fadd_rn(r2, r3)),
                       __fadd_rn(__fadd_rn(r4, r5), __fadd_rn(r6, r7)));
        qn[0]=a.x; qn[1]=a.y; qn[2]=a.z; qn[3]=a.w;
        qn[4]=b.x; qn[5]=b.y; qn[6]=b.z; qn[7]=b.w;
        qn[8]=g.x; qn[9]=g.y; qn[10]=g.z; qn[11]=g.w;
        qn[12]=d.x; qn[13]=d.y; qn[14]=d.z; qn[15]=d.w;
#pragma unroll
        for (int d2 = 0; d2 < DF; ++d2) qn[d2] = -2.0f * qn[d2];
    }
    const f2 q22 = sp2(q2);

    // Sorted (ascending) top-16 as packed u64 keys. Sentinel unflips to 3e38.
    const u64 SENT = ((u64)flip_f(3.0e38f) << 32) | 0xFFFFFFFFull;
    u64   Lk[KNN];
#pragma unroll
    for (int j = 0; j < KNN; ++j) Lk[j] = SENT;
    float tau_reg = 3.0e38f;
    int   cnt = 0;

    // Divergence-free batch drain. Keys rebuilt from the two planes (u16 idx,
    // flip applied at read). Round 1: slots 0..7 (sort8 + keep16 + merge16).
    // Round 2 (rare): slots 8..11 (sort4 + 4 min-pairs + merge16).
    auto drain = [&]() {
        {
            u64 B[8];
#pragma unroll
            for (int e = 0; e < 8; ++e) {
                float de = resd[e * BLK + t];
                u32   ie = (u32)resi[e * BLK + t];
                u64 key = ((u64)flip_f(de) << 32) | ie;
                B[e] = (e < cnt) ? key : SENT;
            }
            // Batcher odd-even mergesort, 8 keys, 19 CEs
            CEB(0,1) CEB(2,3) CEB(4,5) CEB(6,7)
            CEB(0,2) CEB(1,3) CEB(4,6) CEB(5,7)
            CEB(1,2) CEB(5,6)
            CEB(0,4) CEB(1,5) CEB(2,6) CEB(3,7)
            CEB(2,4) CEB(3,5)
            CEB(1,2) CEB(3,4) CEB(5,6)
            // keep-16: L[15-i] = min(L[15-i], B[i]) -> L becomes bitonic
#pragma unroll
            for (int i = 0; i < 8; ++i) {
                u64 a = Lk[KNN - 1 - i], b = B[i];
                Lk[KNN - 1 - i] = (b < a) ? b : a;
            }
            MERGE16()
        }
        if (__any(cnt > 8)) {        // rare second round: slots 8..11
            u64 C[4];
#pragma unroll
            for (int e = 0; e < 4; ++e) {
                float de = resd[(8 + e) * BLK + t];
                u32   ie = (u32)resi[(8 + e) * BLK + t];
                u64 key = ((u64)flip_f(de) << 32) | ie;
                C[e] = (8 + e < cnt) ? key : SENT;
            }
            CEC(0,1) CEC(2,3) CEC(0,2) CEC(1,3) CEC(1,2)   // sort-4
#pragma unroll
            for (int i = 0; i < 4; ++i) {
                u64 a = Lk[KNN - 1 - i], b = C[i];
                Lk[KNN - 1 - i] = (b < a) ? b : a;
            }
            MERGE16()
        }
        cnt = 0;
        const float kth = unflip_f((unsigned)(Lk[KNN - 1] >> 32));
        // Global-tau tightening: publish my wave's 2nd smallest, take the max
        // over the 8 waves (>= global 16th, near-tight), fold with local 16th.
        volatile float* t2 = (volatile float*)tau2_sh;
        t2[wv * QPB + lane] = unflip_f((unsigned)(Lk[1] >> 32));
        float gmax = t2[0 * QPB + lane];
#pragma unroll
        for (int j = 1; j < NCH; ++j) gmax = fmaxf(gmax, t2[j * QPB + lane]);
        const float kth2 = fminf(kth, gmax);
        tau_reg = kth2;
        volatile float* ts = (volatile float*)tau_sh;   // benign-race cons. min
        float cur = ts[lane];
        ts[lane] = fminf(cur, kth2);
    };

    for (int tile = 0; tile < NTILE; ++tile) {
        __syncthreads();   // previous tile fully consumed (also covers tau init)
        {
            // Pair staging: thread (p = t&255, hf = t>>8) assembles the four
            // pf planes for dims [8hf, 8hf+8) of candidates {2p, 2p+1}, plus
            // the half-norm partial s_hf per candidate (exact Phase-A tree:
            // nrm = s0 + s1 with s0=(r0+r1)+(r2+r3), s1=(r4+r5)+(r6+r7)).
            const int p  = t & 255;
            const int hf = t >> 8;              // 0 or 1
            const float4* rowA =
                (const float4*)(xs + (size_t)(tile * TILE + 2 * p) * DF);
            float4 a0 = rowA[hf];               // A dims 4hf..4hf+3
            float4 a2 = rowA[hf + 2];           // A dims 8+4hf..8+4hf+3
            float4 b0 = rowA[hf + 4];           // B dims 4hf..4hf+3
            float4 b2 = rowA[hf + 6];           // B dims 8+4hf..
            const int jb0 = 2 * hf;             // planes for dims 4hf..4hf+3
            const int jb2 = 4 + 2 * hf;         // planes for dims 8+4hf..
            pf[(jb0 + 0) * 256 + p] = (f4){a0.x, b0.x, a0.y, b0.y};
            pf[(jb0 + 1) * 256 + p] = (f4){a0.z, b0.z, a0.w, b0.w};
            pf[(jb2 + 0) * 256 + p] = (f4){a2.x, b2.x, a2.y, b2.y};
            pf[(jb2 + 1) * 256 + p] = (f4){a2.z, b2.z, a2.w, b2.w};
            // half-norm partials (rK = d[k]^2 + d[k+8]^2 pairs live in one hf)
            float ra0 = __fadd_rn(__fmul_rn(a0.x, a0.x), __fmul_rn(a2.x, a2.x));
            float ra1 = __fadd_rn(__fmul_rn(a0.y, a0.y), __fmul_rn(a2.y, a2.y));
            float ra2 = __fadd_rn(__fmul_rn(a0.z, a0.z), __fmul_rn(a2.z, a2.z));
            float ra3 = __fadd_rn(__fmul_rn(a0.w, a0.w), __fmul_rn(a2.w, a2.w));
            float rb0 = __fadd_rn(__fmul_rn(b0.x, b0.x), __fmul_rn(b2.x, b2.x));
            float rb1 = __fadd_rn(__fmul_rn(b0.y, b0.y), __fmul_rn(b2.y, b2.y));
            float rb2 = __fadd_rn(__fmul_rn(b0.z, b0.z), __fmul_rn(b2.z, b2.z));
            float rb3 = __fadd_rn(__fmul_rn(b0.w, b0.w), __fmul_rn(b2.w, b2.w));
            f2 s;
            s.x = __fadd_rn(__fadd_rn(ra0, ra1), __fadd_rn(ra2, ra3));
            s.y = __fadd_rn(__fadd_rn(rb0, rb1), __fadd_rn(rb2, rb3));
            prt[hf * 256 + p] = s;
        }
        __syncthreads();

        const int pb = wv * PAIRS_W;             // pair base in tile

        for (int g = 0; g < PAIRS_W; g += GRPP) {
            const float tsh = ((volatile float*)tau_sh)[lane];
            const float tau = fminf(tsh, tau_reg);
            f2  dd[GRPP];
            u32 gA[GRPP];
            // Load + compute phase: ALL ds_reads precede ALL reservoir stores
            // in program order -> compiler pipelines pair-1 loads under
            // pair-0's fma chain without needing LDS alias analysis.
#pragma unroll
            for (int u = 0; u < GRPP; ++u) {
                const int lp = pb + g + u;       // wave-uniform pair index
                const f4* pp = pf + lp;
                f4 c0 = pp[0 * 256];
                f4 c1 = pp[1 * 256];
                f4 c2 = pp[2 * 256];
                f4 c3 = pp[3 * 256];
                f4 c4 = pp[4 * 256];
                f4 c5 = pp[5 * 256];
                f4 c6 = pp[6 * 256];
                f4 c7 = pp[7 * 256];
                const f2 p0 = prt[lp];
                const f2 p1 = prt[256 + lp];
                f2 acc = {0.f, 0.f};
                acc = fma2(sp2(qn[0]),  c0.lo, acc);
                acc = fma2(sp2(qn[1]),  c0.hi, acc);
                acc = fma2(sp2(qn[2]),  c1.lo, acc);
                acc = fma2(sp2(qn[3]),  c1.hi, acc);
                acc = fma2(sp2(qn[4]),  c2.lo, acc);
                acc = fma2(sp2(qn[5]),  c2.hi, acc);
                acc = fma2(sp2(qn[6]),  c3.lo, acc);
                acc = fma2(sp2(qn[7]),  c3.hi, acc);
                acc = fma2(sp2(qn[8]),  c4.lo, acc);
                acc = fma2(sp2(qn[9]),  c4.hi, acc);
                acc = fma2(sp2(qn[10]), c5.lo, acc);
                acc = fma2(sp2(qn[11]), c5.hi, acc);
                acc = fma2(sp2(qn[12]), c6.lo, acc);
                acc = fma2(sp2(qn[13]), c6.hi, acc);
                acc = fma2(sp2(qn[14]), c7.lo, acc);
                acc = fma2(sp2(qn[15]), c7.hi, acc);
                // dist = (q2 + nc) + dot, nc = s0+s1 -> exact r11 tree,
                // elementwise IEEE adds -> bit-identical distances.
                const f2 nn = p0 + p1;
                dd[u] = (q22 + nn) + acc;
                gA[u] = (u32)(tile * TILE + 2 * lp);
            }
            // Insert phase (GATED, r14-style): stores only on actual inserts
            // (r13's branchless always-store caused the 3.99M conflicts).
#pragma unroll
            for (int u = 0; u < GRPP; ++u) {
                if (dd[u].x <= tau) {            // non-strict: boundary ties
                    const int sl = cnt * BLK + t;
                    resd[sl] = dd[u].x; resi[sl] = (u16)gA[u];
                    ++cnt;
                }
                if (dd[u].y <= tau) {
                    const int sl = cnt * BLK + t;
                    resd[sl] = dd[u].y; resi[sl] = (u16)(gA[u] + 1);
                    ++cnt;
                }
            }
            if (__any(cnt >= FLUSH_AT)) drain();
        }
    }
    if (__any(cnt > 0)) drain();                  // final drain

    // ---- Merge the 8 per-slice lists and emit ------------------------------
    __syncthreads();   // overlay aliases tile + other threads' reservoir slots
#pragma unroll
    for (int j = 0; j < KNN; ++j) {
        lds_d[t * MPAD + j] = unflip_f((unsigned)(Lk[j] >> 32));
        lds_i[t * MPAD + j] = (unsigned short)(Lk[j] & 0xFFFFu);
    }
    __syncthreads();

    if (t < QPB) {
        const int l = t;
        float h[NCH];
        int   hi[NCH];
        int   p[NCH];
#pragma unroll
        for (int w2 = 0; w2 < NCH; ++w2) {
            p[w2]  = 0;
            h[w2]  = lds_d[(w2 * QPB + l) * MPAD];
            hi[w2] = (int)lds_i[(w2 * QPB + l) * MPAD];
        }

        const int    gq = set * NPTS + q0 + l;
        const size_t eb = (size_t)gq * KNN;
        float* osrc = out;
        float* odst = out + (size_t)NEDGE;
        float* odis = out + 2 * (size_t)NEDGE;
        const float srcf = (float)gq;

        for (int e = 0; e < KNN; ++e) {
            // (dist, idx) lexicographic min across the 8 heads — exact stable
            // top-k order (slices are strided, so idx must break ties).
            float best = h[0];
            int   bi   = hi[0];
            int   bw   = 0;
#pragma unroll
            for (int w2 = 1; w2 < NCH; ++w2) {
                const bool better = (h[w2] < best) ||
                                    (h[w2] == best && hi[w2] < bi);
                if (better) { best = h[w2]; bi = hi[w2]; bw = w2; }
            }

#pragma unroll
            for (int w2 = 0; w2 < NCH; ++w2) {
                if (bw == w2) {
                    ++p[w2];
                    if (p[w2] < KNN) {
                        h[w2]  = lds_d[(w2 * QPB + l) * MPAD + p[w2]];
                        hi[w2] = (int)lds_i[(w2 * QPB + l) * MPAD + p[w2]];
                    } else {
                        h[w2]  = 3.0e38f;
                        hi[w2] = 0x7FFFFFFF;
                    }
                }
            }

            osrc[eb + e] = srcf;
            odst[eb + e] = (float)(set * NPTS + bi);
            odis[eb + e] = best;
        }
    }
}

// ---------------------------------------------------------------------------
extern "C" void kernel_launch(void* const* d_in, const int* in_sizes, int n_in,
                              void* d_out, int out_size, void* d_ws, size_t ws_size,
                              hipStream_t stream) {
    (void)in_sizes; (void)n_in; (void)out_size; (void)d_ws; (void)ws_size;
    const float* x = (const float*)d_in[0];  // (8, 4096, 16) f32
    float* out = (float*)d_out;              // [src|dst|dist] f32

    knn_kernel<<<NSETS * (NPTS / QPB), BLK, 0, stream>>>(x, out);
}

// Round 9
// 216.305 us; speedup vs baseline: 1.3699x; 1.3699x over previous
//
#include <hip/hip_runtime.h>

typedef unsigned long long u64;
typedef unsigned int u32;
typedef unsigned short u16;

// Problem constants (match reference setup_inputs)
#define NSETS 8
#define NPTS  4096
#define DF    16
#define KNN   16
#define QPB   64                  // queries per block (one per lane)
#define NCH   8                   // waves per block
#define BLK   (QPB * NCH)         // 512 threads
#define TILE  512                 // candidates staged into LDS per tile
#define NTILE (NPTS / TILE)       // 8
#define SLICE (TILE / NCH)        // 64 candidates per wave per tile
#define NEDGE (NSETS * NPTS * KNN)

// Round-16: r15 closed the pk-FMA line (launch_bounds(512,8) ignored, VGPR
// 88, occ 20.5%). Decomposing r13's 126->93us busy-time win: ~17us was pk
// math (needs the fatal +16 VGPR), ~16us was BRANCHLESSNESS of the insert
// path (v_cmp + exec save/restore + divergent body ~10 instr/cand, executed
// whenever any lane inserts ~ always early). The branchless half works on
// the scalar scan at VGPR 56. r13's 3.99M "conflict storm" was a red
// herring: 0.03 conflicts/store, dist-plane always-store is clean 2-way
// (free, m136). r16 = r14 verbatim + branchless always-store inserts:
// store (dist, u16 idx) to slot cnt unconditionally, cnt += (dist<=tau).
// Slot bound: post-group FLUSH_AT=9 -> cnt<=8 entering group, 4 stores
// touch <= slot 11 < RES=12. Garbage beyond cnt masked by drain's (e<cnt).
// Same distances, same (dist,idx) selection -> output bytes identical.
#define RES      12               // append-list slots/lane
#define FLUSH_AT 9                // drain when any lane cnt >= this (post-group)
#define GRP      4                // candidates between drain checks

#define FEAT_B   (TILE * DF * 4)            // 32768 B: feat4[4][TILE] transposed
#define NRM_B    (TILE * 4)                 // 2048 B:  nrm_t[TILE]
#define RESV_OFF (FEAT_B + NRM_B)           // 34816: dist plane (f32)
#define RESI_OFF (RESV_OFF + RES * BLK * 4) // 59392: idx plane (u16)
#define SMEM_B   (RESI_OFF + RES * BLK * 2) // 71680 B (+2304 tau = 73984 total)
#define MPAD     17                         // merge-overlay stride (17 coprime 32)

// positive/negative-safe orderable-uint mapping for f32 (handles the ~±0
// diagonal self-distance)
__device__ __forceinline__ unsigned flip_f(float d) {
    unsigned b = __float_as_uint(d);
    return (b & 0x80000000u) ? ~b : (b | 0x80000000u);
}
__device__ __forceinline__ float unflip_f(unsigned u) {
    unsigned b = (u & 0x80000000u) ? (u ^ 0x80000000u) : ~u;
    return __uint_as_float(b);
}

// compare-exchange: ascending (min at i), u64 key carries (dist, idx)
#define CEB(i, j) { u64 _a = B[i], _b = B[j]; bool _c = _b < _a; \
                    B[i] = _c ? _b : _a; B[j] = _c ? _a : _b; }
#define CEC(i, j) { u64 _a = C[i], _b = C[j]; bool _c = _b < _a; \
                    C[i] = _c ? _b : _a; C[j] = _c ? _a : _b; }
#define CEL(i, j) { u64 _a = Lk[i], _b = Lk[j]; bool _c = _b < _a; \
                    Lk[i] = _c ? _b : _a; Lk[j] = _c ? _a : _b; }
// bitonic merge 16 -> ascending (Lk[0..7] asc, tail from min-pair => bitonic)
#define MERGE16() \
    CEL(0,8)  CEL(1,9)  CEL(2,10) CEL(3,11)  \
    CEL(4,12) CEL(5,13) CEL(6,14) CEL(7,15)  \
    CEL(0,4)  CEL(1,5)  CEL(2,6)  CEL(3,7)   \
    CEL(8,12) CEL(9,13) CEL(10,14) CEL(11,15) \
    CEL(0,2)  CEL(1,3)  CEL(4,6)  CEL(5,7)   \
    CEL(8,10) CEL(9,11) CEL(12,14) CEL(13,15) \
    CEL(0,1)  CEL(2,3)  CEL(4,5)  CEL(6,7)   \
    CEL(8,9)  CEL(10,11) CEL(12,13) CEL(14,15)

__global__ __launch_bounds__(BLK, 4) void knn_kernel(const float* __restrict__ x,
                                                     float* __restrict__ out) {
    __shared__ float tau_sh[QPB];                 // shared per-query tau (min fold)
    __shared__ float tau2_sh[NCH * QPB];          // per-wave 2nd-smallest per query
    __shared__ __align__(16) char smem[SMEM_B];
    float4* feat4 = (float4*)smem;                // feat4[r*TILE + c], r=0..3
    float*  nrm_t = (float*)(smem + FEAT_B);      // candidate norms
    float*  resd  = (float*)(smem + RESV_OFF);    // reservoir dist plane (f32)
    u16*    resi  = (u16*)(smem + RESI_OFF);      // reservoir idx plane (u16)
    float*          lds_d = (float*)smem;                     // overlay (post-scan)
    unsigned short* lds_i = (unsigned short*)(smem + BLK * MPAD * 4);

    const int t    = threadIdx.x;
    const int lane = t & 63;
    const int wv   = t >> 6;                    // slice index 0..7
    const int set  = blockIdx.x >> 6;           // 64 blocks per set
    const int q0   = (blockIdx.x & 63) * QPB;
    const int q    = q0 + lane;                 // this lane's query point

    const float* xs = x + (size_t)set * NPTS * DF;

    if (t < QPB) tau_sh[t] = 3.0e38f;
    tau2_sh[t] = 3.0e38f;                       // BLK == NCH*QPB, full coverage

    // Query features; q2 via the SAME pairwise tree as candidate norms (bit-
    // identical to prior rounds). qn = -2*q: exact pow2 scaling commutes with
    // fma rounding -> dist bit-identical to r11/r14.
    float qn[DF];
    float q2;
    {
        const float4* qp = (const float4*)(xs + (size_t)q * DF);
        float4 a = qp[0], b = qp[1], g = qp[2], d = qp[3];
        float r0 = __fadd_rn(__fmul_rn(a.x, a.x), __fmul_rn(g.x, g.x));
        float r1 = __fadd_rn(__fmul_rn(a.y, a.y), __fmul_rn(g.y, g.y));
        float r2 = __fadd_rn(__fmul_rn(a.z, a.z), __fmul_rn(g.z, g.z));
        float r3 = __fadd_rn(__fmul_rn(a.w, a.w), __fmul_rn(g.w, g.w));
        float r4 = __fadd_rn(__fmul_rn(b.x, b.x), __fmul_rn(d.x, d.x));
        float r5 = __fadd_rn(__fmul_rn(b.y, b.y), __fmul_rn(d.y, d.y));
        float r6 = __fadd_rn(__fmul_rn(b.z, b.z), __fmul_rn(d.z, d.z));
        float r7 = __fadd_rn(__fmul_rn(b.w, b.w), __fmul_rn(d.w, d.w));
        q2 = __fadd_rn(__fadd_rn(__fadd_rn(r0, r1), __fadd_rn(r2, r3)),
                       __fadd_rn(__fadd_rn(r4, r5), __fadd_rn(r6, r7)));
        qn[0]=a.x; qn[1]=a.y; qn[2]=a.z; qn[3]=a.w;
        qn[4]=b.x; qn[5]=b.y; qn[6]=b.z; qn[7]=b.w;
        qn[8]=g.x; qn[9]=g.y; qn[10]=g.z; qn[11]=g.w;
        qn[12]=d.x; qn[13]=d.y; qn[14]=d.z; qn[15]=d.w;
#pragma unroll
        for (int d2 = 0; d2 < DF; ++d2) qn[d2] = -2.0f * qn[d2];
    }

    // Sorted (ascending) top-16 as packed u64 keys. Sentinel unflips to 3e38.
    const u64 SENT = ((u64)flip_f(3.0e38f) << 32) | 0xFFFFFFFFull;
    u64   Lk[KNN];
#pragma unroll
    for (int j = 0; j < KNN; ++j) Lk[j] = SENT;
    float tau_reg = 3.0e38f;
    int   cnt = 0;

    // Divergence-free batch drain. Keys rebuilt from the two planes (u16 idx,
    // flip applied at read -> same (dist,idx) lex order). Round 1: slots 0..7
    // (sort8 + keep16 + merge16). Round 2 (rare): slots 8..11 (sort4 + 4
    // min-pairs + merge16).
    auto drain = [&]() {
        {
            u64 B[8];
#pragma unroll
            for (int e = 0; e < 8; ++e) {
                float de = resd[e * BLK + t];
                u32   ie = (u32)resi[e * BLK + t];
                u64 key = ((u64)flip_f(de) << 32) | ie;
                B[e] = (e < cnt) ? key : SENT;
            }
            // Batcher odd-even mergesort, 8 keys, 19 CEs
            CEB(0,1) CEB(2,3) CEB(4,5) CEB(6,7)
            CEB(0,2) CEB(1,3) CEB(4,6) CEB(5,7)
            CEB(1,2) CEB(5,6)
            CEB(0,4) CEB(1,5) CEB(2,6) CEB(3,7)
            CEB(2,4) CEB(3,5)
            CEB(1,2) CEB(3,4) CEB(5,6)
            // keep-16: L[15-i] = min(L[15-i], B[i]) -> L becomes bitonic
#pragma unroll
            for (int i = 0; i < 8; ++i) {
                u64 a = Lk[KNN - 1 - i], b = B[i];
                Lk[KNN - 1 - i] = (b < a) ? b : a;
            }
            MERGE16()
        }
        if (__any(cnt > 8)) {        // rare second round: slots 8..11
            u64 C[4];
#pragma unroll
            for (int e = 0; e < 4; ++e) {
                float de = resd[(8 + e) * BLK + t];
                u32   ie = (u32)resi[(8 + e) * BLK + t];
                u64 key = ((u64)flip_f(de) << 32) | ie;
                C[e] = (8 + e < cnt) ? key : SENT;
            }
            CEC(0,1) CEC(2,3) CEC(0,2) CEC(1,3) CEC(1,2)   // sort-4
#pragma unroll
            for (int i = 0; i < 4; ++i) {
                u64 a = Lk[KNN - 1 - i], b = C[i];
                Lk[KNN - 1 - i] = (b < a) ? b : a;
            }
            MERGE16()
        }
        cnt = 0;
        const float kth = unflip_f((unsigned)(Lk[KNN - 1] >> 32));
        // Global-tau tightening: publish my wave's 2nd smallest, take the max
        // over the 8 waves (>= global 16th, near-tight), fold with local 16th.
        volatile float* t2 = (volatile float*)tau2_sh;
        t2[wv * QPB + lane] = unflip_f((unsigned)(Lk[1] >> 32));
        float gmax = t2[0 * QPB + lane];
#pragma unroll
        for (int j = 1; j < NCH; ++j) gmax = fmaxf(gmax, t2[j * QPB + lane]);
        const float kth2 = fminf(kth, gmax);
        tau_reg = kth2;
        volatile float* ts = (volatile float*)tau_sh;   // benign-race cons. min
        float cur = ts[lane];
        ts[lane] = fminf(cur, kth2);
    };

    for (int tile = 0; tile < NTILE; ++tile) {
        __syncthreads();   // previous tile fully consumed (also covers tau init)
        {
            // Thread t stages candidate tile*TILE+t: features (transposed
            // float4 rows) + norm via the exact Phase-A tree, in registers.
            const int c = tile * TILE + t;
            const float4* p = (const float4*)(xs + (size_t)c * DF);
            float4 a = p[0], b = p[1], g = p[2], d = p[3];
            float r0 = __fadd_rn(__fmul_rn(a.x, a.x), __fmul_rn(g.x, g.x));
            float r1 = __fadd_rn(__fmul_rn(a.y, a.y), __fmul_rn(g.y, g.y));
            float r2 = __fadd_rn(__fmul_rn(a.z, a.z), __fmul_rn(g.z, g.z));
            float r3 = __fadd_rn(__fmul_rn(a.w, a.w), __fmul_rn(g.w, g.w));
            float r4 = __fadd_rn(__fmul_rn(b.x, b.x), __fmul_rn(d.x, d.x));
            float r5 = __fadd_rn(__fmul_rn(b.y, b.y), __fmul_rn(d.y, d.y));
            float r6 = __fadd_rn(__fmul_rn(b.z, b.z), __fmul_rn(d.z, d.z));
            float r7 = __fadd_rn(__fmul_rn(b.w, b.w), __fmul_rn(d.w, d.w));
            feat4[0 * TILE + t] = a;
            feat4[1 * TILE + t] = b;
            feat4[2 * TILE + t] = g;
            feat4[3 * TILE + t] = d;
            nrm_t[t] = __fadd_rn(
                __fadd_rn(__fadd_rn(r0, r1), __fadd_rn(r2, r3)),
                __fadd_rn(__fadd_rn(r4, r5), __fadd_rn(r6, r7)));
        }
        __syncthreads();

        const int lbase = wv * SLICE;            // local slice base in tile
        const int gbase = tile * TILE + lbase;   // global candidate id base

        for (int g = 0; g < SLICE; g += GRP) {
            const float tsh = ((volatile float*)tau_sh)[lane];
            const float tau = fminf(tsh, tau_reg);
#pragma unroll
            for (int u = 0; u < GRP; ++u) {
                const int lc = lbase + g + u;    // wave-uniform -> broadcast
                float4 f0 = feat4[0 * TILE + lc];
                float4 f1 = feat4[1 * TILE + lc];
                float4 f2 = feat4[2 * TILE + lc];
                float4 f3 = feat4[3 * TILE + lc];
                const float nc = nrm_t[lc];
                float dot = 0.f;
                dot = fmaf(qn[0],  f0.x, dot); dot = fmaf(qn[1],  f0.y, dot);
                dot = fmaf(qn[2],  f0.z, dot); dot = fmaf(qn[3],  f0.w, dot);
                dot = fmaf(qn[4],  f1.x, dot); dot = fmaf(qn[5],  f1.y, dot);
                dot = fmaf(qn[6],  f1.z, dot); dot = fmaf(qn[7],  f1.w, dot);
                dot = fmaf(qn[8],  f2.x, dot); dot = fmaf(qn[9],  f2.y, dot);
                dot = fmaf(qn[10], f2.z, dot); dot = fmaf(qn[11], f2.w, dot);
                dot = fmaf(qn[12], f3.x, dot); dot = fmaf(qn[13], f3.y, dot);
                dot = fmaf(qn[14], f3.z, dot); dot = fmaf(qn[15], f3.w, dot);
                const float dist = __fadd_rn(__fadd_rn(q2, nc), dot);
                // Branchless insert: always store to slot cnt (entries beyond
                // cnt are never read — drain masks with e<cnt), bump cnt only
                // on pass. No exec-mask branch -> the 4 fma chains + stores
                // pipeline freely. Max slot touched: 8 (pre-group bound) + 3
                // = 11 < RES=12.
                const int sl = cnt * BLK + t;
                resd[sl] = dist;
                resi[sl] = (u16)(gbase + g + u);
                cnt += (dist <= tau) ? 1 : 0;    // non-strict: keep boundary ties
            }
            if (__any(cnt >= FLUSH_AT)) drain();
        }
    }
    if (__any(cnt > 0)) drain();                  // final drain

    // ---- Merge the 8 per-slice lists and emit ------------------------------
    __syncthreads();   // overlay aliases tile + other threads' reservoir slots
#pragma unroll
    for (int j = 0; j < KNN; ++j) {
        lds_d[t * MPAD + j] = unflip_f((unsigned)(Lk[j] >> 32));
        lds_i[t * MPAD + j] = (unsigned short)(Lk[j] & 0xFFFFu);
    }
    __syncthreads();

    if (t < QPB) {
        const int l = t;
        float h[NCH];
        int   hi[NCH];
        int   p[NCH];
#pragma unroll
        for (int w2 = 0; w2 < NCH; ++w2) {
            p[w2]  = 0;
            h[w2]  = lds_d[(w2 * QPB + l) * MPAD];
            hi[w2] = (int)lds_i[(w2 * QPB + l) * MPAD];
        }

        const int    gq = set * NPTS + q0 + l;
        const size_t eb = (size_t)gq * KNN;
        float* osrc = out;
        float* odst = out + (size_t)NEDGE;
        float* odis = out + 2 * (size_t)NEDGE;
        const float srcf = (float)gq;

        for (int e = 0; e < KNN; ++e) {
            // (dist, idx) lexicographic min across the 8 heads — exact stable
            // top-k order (slices are strided, so idx must break ties).
            float best = h[0];
            int   bi   = hi[0];
            int   bw   = 0;
#pragma unroll
            for (int w2 = 1; w2 < NCH; ++w2) {
                const bool better = (h[w2] < best) ||
                                    (h[w2] == best && hi[w2] < bi);
                if (better) { best = h[w2]; bi = hi[w2]; bw = w2; }
            }

#pragma unroll
            for (int w2 = 0; w2 < NCH; ++w2) {
                if (bw == w2) {
                    ++p[w2];
                    if (p[w2] < KNN) {
                        h[w2]  = lds_d[(w2 * QPB + l) * MPAD + p[w2]];
                        hi[w2] = (int)lds_i[(w2 * QPB + l) * MPAD + p[w2]];
                    } else {
                        h[w2]  = 3.0e38f;
                        hi[w2] = 0x7FFFFFFF;
                    }
                }
            }

            osrc[eb + e] = srcf;
            odst[eb + e] = (float)(set * NPTS + bi);
            odis[eb + e] = best;
        }
    }
}

// ---------------------------------------------------------------------------
extern "C" void kernel_launch(void* const* d_in, const int* in_sizes, int n_in,
                              void* d_out, int out_size, void* d_ws, size_t ws_size,
                              hipStream_t stream) {
    (void)in_sizes; (void)n_in; (void)out_size; (void)d_ws; (void)ws_size;
    const float* x = (const float*)d_in[0];  // (8, 4096, 16) f32
    float* out = (float*)d_out;              // [src|dst|dist] f32

    knn_kernel<<<NSETS * (NPTS / QPB), BLK, 0, stream>>>(x, out);
}

// Round 10
// 199.735 us; speedup vs baseline: 1.4835x; 1.0830x over previous
//
#include <hip/hip_runtime.h>

typedef unsigned long long u64;

// Problem constants (match reference setup_inputs)
#define NSETS 8
#define NPTS  4096
#define DF    16
#define KNN   16
#define QPB   64                  // queries per block (one per lane)
#define NCH   8                   // waves per block
#define BLK   (QPB * NCH)         // 512 threads
#define TILE  512                 // candidates staged into LDS per tile
#define NTILE (NPTS / TILE)       // 8
#define SLICE (TILE / NCH)        // 64 candidates per wave per tile
#define NEDGE (NSETS * NPTS * KNN)

// Round-17: champion restore (= r11, 166us rocprof / 199.8us harness).
// Session ledger: r10 RES10 (180), r11 +global-tau2 (166, champion),
// r12/r13/r15 pk-FMA (VGPR>64 occupancy cliff, 230-278), r14 u16-key
// RES12 (174, key-rebuild cancels drain savings), r16 branchless insert
// (185.5, always-stores cost more than branch overhead saved). All
// selection-machinery levers measured; r11 is the structural floor:
// VALU-issue-bound (VALUBusy 76-81%, HBM 1%), occupancy capped at
// 2 blocks/CU by grid geometry (512 blocks / 256 CU). Key invariants:
// VGPR must stay <=64 (else 1 block/CU), gated inserts beat branchless,
// RES=10/FLUSH=7 with u64 reservoir keys is the measured optimum.
// tau = min(local 16th, max_j(wave j's 2nd smallest)) — sound and
// near-tight (2/512 quantile == 16/4096); output exact (dist,idx)-lex
// top-k, bit-identical to reference stable order.
#define RES      10               // append-list slots/lane
#define FLUSH_AT 7                // drain when any lane cnt >= this (post-group)
#define GRP      4                // candidates between drain checks

#define FEAT_B   (TILE * DF * 4)            // 32768 B: feat4[4][TILE] transposed
#define NRM_B    (TILE * 4)                 // 2048 B:  nrm_t[TILE]
#define RESV_OFF (FEAT_B + NRM_B)           // 34816
#define SMEM_B   (RESV_OFF + RES * BLK * 8) // 75776 B (+tau arrays -> 2 blocks/CU)
#define MPAD     17                         // merge-overlay stride (17 coprime 32)

// positive/negative-safe orderable-uint mapping for f32 (handles the ~±0
// diagonal self-distance)
__device__ __forceinline__ unsigned flip_f(float d) {
    unsigned b = __float_as_uint(d);
    return (b & 0x80000000u) ? ~b : (b | 0x80000000u);
}
__device__ __forceinline__ float unflip_f(unsigned u) {
    unsigned b = (u & 0x80000000u) ? (u ^ 0x80000000u) : ~u;
    return __uint_as_float(b);
}

// compare-exchange: ascending (min at i), u64 key carries (dist, idx)
#define CEB(i, j) { u64 _a = B[i], _b = B[j]; bool _c = _b < _a; \
                    B[i] = _c ? _b : _a; B[j] = _c ? _a : _b; }
#define CEL(i, j) { u64 _a = Lk[i], _b = Lk[j]; bool _c = _b < _a; \
                    Lk[i] = _c ? _b : _a; Lk[j] = _c ? _a : _b; }
// bitonic merge 16 -> ascending (Lk[0..7] asc, Lk[8..15] from min-pair => bitonic)
#define MERGE16() \
    CEL(0,8)  CEL(1,9)  CEL(2,10) CEL(3,11)  \
    CEL(4,12) CEL(5,13) CEL(6,14) CEL(7,15)  \
    CEL(0,4)  CEL(1,5)  CEL(2,6)  CEL(3,7)   \
    CEL(8,12) CEL(9,13) CEL(10,14) CEL(11,15) \
    CEL(0,2)  CEL(1,3)  CEL(4,6)  CEL(5,7)   \
    CEL(8,10) CEL(9,11) CEL(12,14) CEL(13,15) \
    CEL(0,1)  CEL(2,3)  CEL(4,5)  CEL(6,7)   \
    CEL(8,9)  CEL(10,11) CEL(12,13) CEL(14,15)

__global__ __launch_bounds__(BLK) void knn_kernel(const float* __restrict__ x,
                                                  float* __restrict__ out) {
    __shared__ float tau_sh[QPB];                 // shared per-query tau (min fold)
    __shared__ float tau2_sh[NCH * QPB];          // per-wave 2nd-smallest per query
    __shared__ __align__(16) char smem[SMEM_B];
    float4* feat4 = (float4*)smem;                // feat4[r*TILE + c], r=0..3
    float*  nrm_t = (float*)(smem + FEAT_B);      // candidate norms
    u64*    resv  = (u64*)(smem + RESV_OFF);      // resv[slot*BLK + t], u64 keys
    float*          lds_d = (float*)smem;                     // overlay (post-scan)
    unsigned short* lds_i = (unsigned short*)(smem + BLK * MPAD * 4);

    const int t    = threadIdx.x;
    const int lane = t & 63;
    const int wv   = t >> 6;                    // slice index 0..7
    const int set  = blockIdx.x >> 6;           // 64 blocks per set
    const int q0   = (blockIdx.x & 63) * QPB;
    const int q    = q0 + lane;                 // this lane's query point

    const float* xs = x + (size_t)set * NPTS * DF;

    if (t < QPB) tau_sh[t] = 3.0e38f;
    tau2_sh[t] = 3.0e38f;                       // BLK == NCH*QPB, full coverage

    // Query features; q2 via the SAME pairwise tree as candidate norms (bit-
    // identical to prior rounds). qn = -2*q: exact pow2 scaling commutes with
    // fma rounding -> dist bit-identical across rounds.
    float qn[DF];
    float q2;
    {
        const float4* qp = (const float4*)(xs + (size_t)q * DF);
        float4 a = qp[0], b = qp[1], g = qp[2], d = qp[3];
        float r0 = __fadd_rn(__fmul_rn(a.x, a.x), __fmul_rn(g.x, g.x));
        float r1 = __fadd_rn(__fmul_rn(a.y, a.y), __fmul_rn(g.y, g.y));
        float r2 = __fadd_rn(__fmul_rn(a.z, a.z), __fmul_rn(g.z, g.z));
        float r3 = __fadd_rn(__fmul_rn(a.w, a.w), __fmul_rn(g.w, g.w));
        float r4 = __fadd_rn(__fmul_rn(b.x, b.x), __fmul_rn(d.x, d.x));
        float r5 = __fadd_rn(__fmul_rn(b.y, b.y), __fmul_rn(d.y, d.y));
        float r6 = __fadd_rn(__fmul_rn(b.z, b.z), __fmul_rn(d.z, d.z));
        float r7 = __fadd_rn(__fmul_rn(b.w, b.w), __fmul_rn(d.w, d.w));
        q2 = __fadd_rn(__fadd_rn(__fadd_rn(r0, r1), __fadd_rn(r2, r3)),
                       __fadd_rn(__fadd_rn(r4, r5), __fadd_rn(r6, r7)));
        qn[0]=a.x; qn[1]=a.y; qn[2]=a.z; qn[3]=a.w;
        qn[4]=b.x; qn[5]=b.y; qn[6]=b.z; qn[7]=b.w;
        qn[8]=g.x; qn[9]=g.y; qn[10]=g.z; qn[11]=g.w;
        qn[12]=d.x; qn[13]=d.y; qn[14]=d.z; qn[15]=d.w;
#pragma unroll
        for (int d2 = 0; d2 < DF; ++d2) qn[d2] = -2.0f * qn[d2];
    }

    // Sorted (ascending) top-16 as packed u64 keys. Sentinel unflips to 3e38.
    const u64 SENT = ((u64)flip_f(3.0e38f) << 32) | 0xFFFFFFFFull;
    u64   Lk[KNN];
#pragma unroll
    for (int j = 0; j < KNN; ++j) Lk[j] = SENT;
    float tau_reg = 3.0e38f;
    int   cnt = 0;

    // Divergence-free batch drain: sort slots 0..7 (sentinel-padded per lane),
    // min-pair into the tail of Lk (keeps the 16 smallest, leaves Lk bitonic),
    // bitonic-merge-16 back to sorted. Second round (rare) covers slots 8..9.
    // Key order is exact (dist, idx) lexicographic == reference stable order.
    auto drain = [&]() {
        {
            u64 B[8];
#pragma unroll
            for (int e = 0; e < 8; ++e) {
                u64 v = resv[e * BLK + t];
                B[e] = (e < cnt) ? v : SENT;
            }
            // Batcher odd-even mergesort, 8 keys, 19 CEs
            CEB(0,1) CEB(2,3) CEB(4,5) CEB(6,7)
            CEB(0,2) CEB(1,3) CEB(4,6) CEB(5,7)
            CEB(1,2) CEB(5,6)
            CEB(0,4) CEB(1,5) CEB(2,6) CEB(3,7)
            CEB(2,4) CEB(3,5)
            CEB(1,2) CEB(3,4) CEB(5,6)
            // keep-16: L[15-i] = min(L[15-i], B[i]) -> L becomes bitonic
#pragma unroll
            for (int i = 0; i < 8; ++i) {
                u64 a = Lk[KNN - 1 - i], b = B[i];
                Lk[KNN - 1 - i] = (b < a) ? b : a;
            }
            MERGE16()
        }
        if (__any(cnt > 8)) {        // rare second round: slots 8..9
            u64 c0 = resv[8 * BLK + t];
            u64 c1 = resv[9 * BLK + t];
            c0 = (8 < cnt) ? c0 : SENT;
            c1 = (9 < cnt) ? c1 : SENT;
            { u64 a = c0, b = c1; bool c = b < a; c0 = c ? b : a; c1 = c ? a : b; }
            { u64 a = Lk[15]; Lk[15] = (c0 < a) ? c0 : a; }
            { u64 a = Lk[14]; Lk[14] = (c1 < a) ? c1 : a; }
            MERGE16()
        }
        cnt = 0;
        const float kth = unflip_f((unsigned)(Lk[KNN - 1] >> 32));
        // Global-tau tightening: publish my wave's 2nd smallest, take the max
        // over the 8 waves (>= global 16th, near-tight), fold with local 16th.
        volatile float* t2 = (volatile float*)tau2_sh;
        t2[wv * QPB + lane] = unflip_f((unsigned)(Lk[1] >> 32));
        float gmax = t2[0 * QPB + lane];
#pragma unroll
        for (int j = 1; j < NCH; ++j) gmax = fmaxf(gmax, t2[j * QPB + lane]);
        const float kth2 = fminf(kth, gmax);
        tau_reg = kth2;
        volatile float* ts = (volatile float*)tau_sh;   // benign-race cons. min
        float cur = ts[lane];
        ts[lane] = fminf(cur, kth2);
    };

    for (int tile = 0; tile < NTILE; ++tile) {
        __syncthreads();   // previous tile fully consumed (also covers tau init)
        {
            // Thread t stages candidate tile*TILE+t: features (transposed
            // float4 rows) + norm via the exact Phase-A tree, in registers.
            const int c = tile * TILE + t;
            const float4* p = (const float4*)(xs + (size_t)c * DF);
            float4 a = p[0], b = p[1], g = p[2], d = p[3];
            float r0 = __fadd_rn(__fmul_rn(a.x, a.x), __fmul_rn(g.x, g.x));
            float r1 = __fadd_rn(__fmul_rn(a.y, a.y), __fmul_rn(g.y, g.y));
            float r2 = __fadd_rn(__fmul_rn(a.z, a.z), __fmul_rn(g.z, g.z));
            float r3 = __fadd_rn(__fmul_rn(a.w, a.w), __fmul_rn(g.w, g.w));
            float r4 = __fadd_rn(__fmul_rn(b.x, b.x), __fmul_rn(d.x, d.x));
            float r5 = __fadd_rn(__fmul_rn(b.y, b.y), __fmul_rn(d.y, d.y));
            float r6 = __fadd_rn(__fmul_rn(b.z, b.z), __fmul_rn(d.z, d.z));
            float r7 = __fadd_rn(__fmul_rn(b.w, b.w), __fmul_rn(d.w, d.w));
            feat4[0 * TILE + t] = a;
            feat4[1 * TILE + t] = b;
            feat4[2 * TILE + t] = g;
            feat4[3 * TILE + t] = d;
            nrm_t[t] = __fadd_rn(
                __fadd_rn(__fadd_rn(r0, r1), __fadd_rn(r2, r3)),
                __fadd_rn(__fadd_rn(r4, r5), __fadd_rn(r6, r7)));
        }
        __syncthreads();

        const int lbase = wv * SLICE;            // local slice base in tile
        const int gbase = tile * TILE + lbase;   // global candidate id base

        for (int g = 0; g < SLICE; g += GRP) {
            const float tsh = ((volatile float*)tau_sh)[lane];
            const float tau = fminf(tsh, tau_reg);
#pragma unroll
            for (int u = 0; u < GRP; ++u) {
                const int lc = lbase + g + u;    // wave-uniform -> broadcast
                float4 f0 = feat4[0 * TILE + lc];
                float4 f1 = feat4[1 * TILE + lc];
                float4 f2 = feat4[2 * TILE + lc];
                float4 f3 = feat4[3 * TILE + lc];
                const float nc = nrm_t[lc];
                float dot = 0.f;
                dot = fmaf(qn[0],  f0.x, dot); dot = fmaf(qn[1],  f0.y, dot);
                dot = fmaf(qn[2],  f0.z, dot); dot = fmaf(qn[3],  f0.w, dot);
                dot = fmaf(qn[4],  f1.x, dot); dot = fmaf(qn[5],  f1.y, dot);
                dot = fmaf(qn[6],  f1.z, dot); dot = fmaf(qn[7],  f1.w, dot);
                dot = fmaf(qn[8],  f2.x, dot); dot = fmaf(qn[9],  f2.y, dot);
                dot = fmaf(qn[10], f2.z, dot); dot = fmaf(qn[11], f2.w, dot);
                dot = fmaf(qn[12], f3.x, dot); dot = fmaf(qn[13], f3.y, dot);
                dot = fmaf(qn[14], f3.z, dot); dot = fmaf(qn[15], f3.w, dot);
                const float dist = __fadd_rn(__fadd_rn(q2, nc), dot);
                if (dist <= tau) {               // non-strict: keep boundary ties
                    resv[cnt * BLK + t] =
                        ((u64)flip_f(dist) << 32) | (unsigned)(gbase + g + u);
                    ++cnt;
                }
            }
            if (__any(cnt >= FLUSH_AT)) drain();
        }
    }
    if (__any(cnt > 0)) drain();                  // final drain

    // ---- Merge the 8 per-slice lists and emit ------------------------------
    __syncthreads();   // overlay aliases tile + other threads' reservoir slots
#pragma unroll
    for (int j = 0; j < KNN; ++j) {
        lds_d[t * MPAD + j] = unflip_f((unsigned)(Lk[j] >> 32));
        lds_i[t * MPAD + j] = (unsigned short)(Lk[j] & 0xFFFFu);
    }
    __syncthreads();

    if (t < QPB) {
        const int l = t;
        float h[NCH];
        int   hi[NCH];
        int   p[NCH];
#pragma unroll
        for (int w2 = 0; w2 < NCH; ++w2) {
            p[w2]  = 0;
            h[w2]  = lds_d[(w2 * QPB + l) * MPAD];
            hi[w2] = (int)lds_i[(w2 * QPB + l) * MPAD];
        }

        const int    gq = set * NPTS + q0 + l;
        const size_t eb = (size_t)gq * KNN;
        float* osrc = out;
        float* odst = out + (size_t)NEDGE;
        float* odis = out + 2 * (size_t)NEDGE;
        const float srcf = (float)gq;

        for (int e = 0; e < KNN; ++e) {
            // (dist, idx) lexicographic min across the 8 heads — exact stable
            // top-k order (slices are strided, so idx must break ties).
            float best = h[0];
            int   bi   = hi[0];
            int   bw   = 0;
#pragma unroll
            for (int w2 = 1; w2 < NCH; ++w2) {
                const bool better = (h[w2] < best) ||
                                    (h[w2] == best && hi[w2] < bi);
                if (better) { best = h[w2]; bi = hi[w2]; bw = w2; }
            }

#pragma unroll
            for (int w2 = 0; w2 < NCH; ++w2) {
                if (bw == w2) {
                    ++p[w2];
                    if (p[w2] < KNN) {
                        h[w2]  = lds_d[(w2 * QPB + l) * MPAD + p[w2]];
                        hi[w2] = (int)lds_i[(w2 * QPB + l) * MPAD + p[w2]];
                    } else {
                        h[w2]  = 3.0e38f;
                        hi[w2] = 0x7FFFFFFF;
                    }
                }
            }

            osrc[eb + e] = srcf;
            odst[eb + e] = (float)(set * NPTS + bi);
            odis[eb + e] = best;
        }
    }
}

// ---------------------------------------------------------------------------
extern "C" void kernel_launch(void* const* d_in, const int* in_sizes, int n_in,
                              void* d_out, int out_size, void* d_ws, size_t ws_size,
                              hipStream_t stream) {
    (void)in_sizes; (void)n_in; (void)out_size; (void)d_ws; (void)ws_size;
    const float* x = (const float*)d_in[0];  // (8, 4096, 16) f32
    float* out = (float*)d_out;              // [src|dst|dist] f32

    knn_kernel<<<NSETS * (NPTS / QPB), BLK, 0, stream>>>(x, out);
}